// Round 20
// baseline (355.171 us; speedup 1.0000x reference)
//
#include <hip/hip_runtime.h>
#include <hip/hip_bf16.h>
#include <math.h>

// ---------------- constants ----------------
#define IN_DIM 256
#define HID 64
#define HEADS 4
#define HC (HEADS * HID)   // 256
#define OUTC 64
#define NEG_SLOPE 0.2f

typedef unsigned int uint;
typedef unsigned short ushortt;
typedef __attribute__((ext_vector_type(8))) short short8v;
typedef __attribute__((ext_vector_type(4))) float floatx4;

union U8 { uint u[4]; short8v v; };

__device__ __forceinline__ float lrelu(float x) {
    return x >= 0.f ? x : NEG_SLOPE * x;
}
__device__ __forceinline__ float elu1(float x) {
    return x > 0.f ? x : expm1f(x);
}
__device__ __forceinline__ ushortt f2bf(float f) {   // RNE
    uint x = __float_as_uint(f);
    uint r = (x + 0x7fffu + ((x >> 16) & 1u)) >> 16;
    return (ushortt)r;
}
__device__ __forceinline__ float bf2f(ushortt u) {
    return __uint_as_float(((uint)u) << 16);
}

// pack 2 floats -> (hi bf16 pair, lo bf16 pair), RNE (matches f2bf bit-exactly)
#define CVTPAIR(fx, fy, ho, qo)                                                 \
    asm("v_cvt_pk_bf16_f32 %0, %1, %2" : "=v"(ho) : "v"(fx), "v"(fy));          \
    {                                                                           \
        float _r0 = (fx) - __uint_as_float((ho) << 16);                         \
        float _r1 = (fy) - __uint_as_float((ho) & 0xffff0000u);                 \
        asm("v_cvt_pk_bf16_f32 %0, %1, %2" : "=v"(qo) : "v"(_r0), "v"(_r1));    \
    }

// ---------------- W split body (interleaved planes) ----------------
// W layout: Wt[kb(32)][col(N)][hi8|lo8]
__device__ __forceinline__ void wsplit_body(const float* __restrict__ W,
                                            ushortt* __restrict__ Wt, int N,
                                            int b, int tid) {
    int idx = b * 256 + tid;            // < 256*N
    int j = idx & 7;
    int col = (idx >> 3) % N;
    int kb = (idx >> 3) / N;            // 0..31
    float wv = W[(size_t)(kb * 8 + j) * N + col];
    ushortt hi = f2bf(wv);
    ushortt lo = f2bf(wv - bf2f(hi));
    size_t o = ((size_t)kb * N + col) * 16 + j;
    Wt[o] = hi;
    Wt[o + 8] = lo;
}

// ---------------- fused: W splits + edge counting ----------------
__global__ __launch_bounds__(256) void count_prep(
        const float* __restrict__ W1, const float* __restrict__ W2,
        const float* __restrict__ W3,
        ushortt* __restrict__ Wt1, ushortt* __restrict__ Wt2,
        ushortt* __restrict__ Wt3,
        const int* __restrict__ dst, int* __restrict__ counts, int E) {
    int b = blockIdx.x, tid = threadIdx.x;
    if (b < 256) { wsplit_body(W1, Wt1, 256, b, tid); return; }
    if (b < 512) { wsplit_body(W2, Wt2, 256, b - 256, tid); return; }
    if (b < 576) { wsplit_body(W3, Wt3, 64, b - 512, tid); return; }
    int e = (b - 576) * 256 + tid;
    if (e < E) atomicAdd(&counts[dst[e]], 1);
}

// merged bsums-prefix + add; also writes work[] = ptr[] (start offsets)
__global__ void scan_add(int* __restrict__ ptr, const int* __restrict__ bsums,
                         int* __restrict__ work, int n) {
    __shared__ int pre;
    int seg = blockIdx.x >> 2;
    if (threadIdx.x == 0) {
        int s = 0;
        for (int b = 0; b < seg; b++) s += bsums[b];
        pre = s;
    }
    __syncthreads();
    int i = blockIdx.x * 256 + threadIdx.x;
    if (i == 0) { ptr[0] = 0; work[0] = 0; }
    if (i < n) {
        int v = ptr[i + 1] + pre;
        ptr[i + 1] = v;
        if (i + 1 < n) work[i + 1] = v;
    }
}

// stores src*64 (pre-scaled row index)
__global__ void scatter_edges(const int* __restrict__ src, const int* __restrict__ dst,
                              int* __restrict__ work, int* __restrict__ ssrc, int E) {
    int e = blockIdx.x * blockDim.x + threadIdx.x;
    if (e < E) {
        int p = atomicAdd(&work[dst[e]], 1);
        ssrc[p] = src[e] * 64;
    }
}

// ---------------- MFMA GEMM layers 1/2: N=256, 2x2 wave tiling ------------
// F32A (layer 1): fp32 A, 3-term split-bf16, hosts the CSR block-scan in
// extra blocks. !F32A (layer 2): bf16 row-major A (single plane), 2-term.
template<bool F32A>
__global__ __launch_bounds__(256, 3) void gemm_mfma(
        const ushortt* __restrict__ Ai, const float* __restrict__ Af,
        const ushortt* __restrict__ Wt,
        ushortt* __restrict__ Chi, int M,
        const float* __restrict__ a_src, const float* __restrict__ a_dst,
        float* __restrict__ alS, float* __restrict__ alD,
        const int* __restrict__ counts, int* __restrict__ ptrOut,
        int* __restrict__ bsums, int nScan, int gemmBlocks) {
    constexpr int N = 256;
    if constexpr (F32A) {
        if ((int)blockIdx.x >= gemmBlocks) {
            // ---- block scan of counts (1024 per block) ----
            __shared__ int sm[256];
            int sb = blockIdx.x - gemmBlocks;
            int t = threadIdx.x;
            int i = sb * 1024 + t * 4;
            int v0 = 0, v1 = 0, v2 = 0, v3 = 0;
            if (i + 0 < nScan) v0 = counts[i + 0];
            if (i + 1 < nScan) v1 = counts[i + 1];
            if (i + 2 < nScan) v2 = counts[i + 2];
            if (i + 3 < nScan) v3 = counts[i + 3];
            int s1 = v0 + v1, s2 = s1 + v2, s3 = s2 + v3;
            sm[t] = s3;
            __syncthreads();
            for (int off = 1; off < 256; off <<= 1) {
                int add = (t >= off) ? sm[t - off] : 0;
                __syncthreads();
                sm[t] += add;
                __syncthreads();
            }
            int pre = (t > 0) ? sm[t - 1] : 0;
            if (i + 0 < nScan) ptrOut[i + 1] = pre + v0;
            if (i + 1 < nScan) ptrOut[i + 2] = pre + s1;
            if (i + 2 < nScan) ptrOut[i + 3] = pre + s2;
            if (i + 3 < nScan) ptrOut[i + 4] = pre + s3;
            if (t == 255) bsums[sb] = sm[255];
            return;
        }
    }

    int t = threadIdx.x;
    int wid = t >> 6, l = t & 63, l15 = l & 15, chunk = l >> 4;
    int wr = wid >> 1, wc = wid & 1;
    int row0 = blockIdx.x * 64;
    int colw = wc * 128;

    floatx4 acc[2][8];
    floatx4 zero = {0.f, 0.f, 0.f, 0.f};
#pragma unroll
    for (int mt = 0; mt < 2; mt++)
#pragma unroll
        for (int nt = 0; nt < 8; nt++) acc[mt][nt] = zero;

    size_t arow[2];
#pragma unroll
    for (int mt = 0; mt < 2; mt++) {
        int r = row0 + wr * 32 + mt * 16 + l15;
        int rc = r < M ? r : M - 1;
        arow[mt] = (size_t)rc * 256;
    }

    for (int ks = 0; ks < 8; ks++) {
        int kb = ks * 4 + chunk;
        short8v ah[2], aq[2];
        if constexpr (F32A) {
#pragma unroll
            for (int mt = 0; mt < 2; mt++) {
                const float* ap = Af + arow[mt] + kb * 8;
                float4 a0 = ((const float4*)ap)[0];
                float4 a1 = ((const float4*)ap)[1];
                U8 h, q;
                CVTPAIR(a0.x, a0.y, h.u[0], q.u[0]);
                CVTPAIR(a0.z, a0.w, h.u[1], q.u[1]);
                CVTPAIR(a1.x, a1.y, h.u[2], q.u[2]);
                CVTPAIR(a1.z, a1.w, h.u[3], q.u[3]);
                ah[mt] = h.v; aq[mt] = q.v;
            }
        } else {
#pragma unroll
            for (int mt = 0; mt < 2; mt++) {
                ah[mt] = *(const short8v*)(Ai + arow[mt] + kb * 8);
            }
        }
        const ushortt* bbase = Wt + ((size_t)kb * N + colw + l15) * 16;
#pragma unroll
        for (int half = 0; half < 2; half++) {
            short8v bh[4], bq[4];
#pragma unroll
            for (int nt = 0; nt < 4; nt++) {
                const ushortt* bp = bbase + (size_t)(half * 4 + nt) * 256;
                bh[nt] = *(const short8v*)bp;
                bq[nt] = *(const short8v*)(bp + 8);
            }
#pragma unroll
            for (int mt = 0; mt < 2; mt++)
#pragma unroll
                for (int nt = 0; nt < 4; nt++) {
                    int c = half * 4 + nt;
                    if constexpr (F32A)
                        acc[mt][c] = __builtin_amdgcn_mfma_f32_16x16x32_bf16(aq[mt], bh[nt], acc[mt][c], 0, 0, 0);
                    acc[mt][c] = __builtin_amdgcn_mfma_f32_16x16x32_bf16(ah[mt], bq[nt], acc[mt][c], 0, 0, 0);
                    acc[mt][c] = __builtin_amdgcn_mfma_f32_16x16x32_bf16(ah[mt], bh[nt], acc[mt][c], 0, 0, 0);
                }
        }
    }

    // C store
#pragma unroll
    for (int mt = 0; mt < 2; mt++)
#pragma unroll
        for (int j = 0; j < 4; j++) {
            int r = row0 + wr * 32 + mt * 16 + chunk * 4 + j;
            if (r < M) {
#pragma unroll
                for (int nt = 0; nt < 8; nt++)
                    Chi[(size_t)r * N + colw + nt * 16 + l15] = f2bf(acc[mt][nt][j]);
            }
        }

    // fused attention logits: this wave covers heads wc*2 and wc*2+1
    {
        float aSv[8], aDv[8];
#pragma unroll
        for (int nt = 0; nt < 8; nt++) {
            aSv[nt] = a_src[colw + nt * 16 + l15];
            aDv[nt] = a_dst[colw + nt * 16 + l15];
        }
#pragma unroll
        for (int mt = 0; mt < 2; mt++)
#pragma unroll
            for (int j = 0; j < 4; j++) {
                float s0 = 0.f, d0 = 0.f, s1 = 0.f, d1 = 0.f;
#pragma unroll
                for (int nt = 0; nt < 4; nt++) {
                    s0 += acc[mt][nt][j] * aSv[nt];
                    d0 += acc[mt][nt][j] * aDv[nt];
                    s1 += acc[mt][nt + 4][j] * aSv[nt + 4];
                    d1 += acc[mt][nt + 4][j] * aDv[nt + 4];
                }
#pragma unroll
                for (int off = 1; off < 16; off <<= 1) {
                    s0 += __shfl_xor(s0, off);
                    d0 += __shfl_xor(d0, off);
                    s1 += __shfl_xor(s1, off);
                    d1 += __shfl_xor(d1, off);
                }
                int r = row0 + wr * 32 + mt * 16 + chunk * 4 + j;
                if (l15 == 0 && r < M) {
                    alS[(size_t)r * 4 + wc * 2 + 0] = s0;
                    alS[(size_t)r * 4 + wc * 2 + 1] = s1;
                    alD[(size_t)r * 4 + wc * 2 + 0] = d0;
                    alD[(size_t)r * 4 + wc * 2 + 1] = d1;
                }
            }
    }
}

// ---------------- MFMA GEMM layer 3: N=64, bf16 A (row-major), 2-term ----
__global__ __launch_bounds__(256) void gemm_n64(
        const ushortt* __restrict__ Ai, const ushortt* __restrict__ Wt,
        ushortt* __restrict__ Chi, int M,
        const float* __restrict__ a_src, const float* __restrict__ a_dst,
        float* __restrict__ alS, float* __restrict__ alD) {
    constexpr int N = 64;
    int t = threadIdx.x;
    int wid = t >> 6, l = t & 63, l15 = l & 15, chunk = l >> 4;
    int row0 = blockIdx.x * 64;
    int rw = row0 + wid * 16 + l15;
    size_t arow = (size_t)(rw < M ? rw : M - 1) * 256;

    floatx4 acc[4];
    floatx4 zero = {0.f, 0.f, 0.f, 0.f};
#pragma unroll
    for (int nt = 0; nt < 4; nt++) acc[nt] = zero;

    for (int ks = 0; ks < 8; ks++) {
        int kb = ks * 4 + chunk;
        short8v bh[4], bq[4];
#pragma unroll
        for (int nt = 0; nt < 4; nt++) {
            const ushortt* bp = Wt + ((size_t)kb * N + nt * 16 + l15) * 16;
            bh[nt] = *(const short8v*)bp;
            bq[nt] = *(const short8v*)(bp + 8);
        }
        short8v ah = *(const short8v*)(Ai + arow + kb * 8);
#pragma unroll
        for (int nt = 0; nt < 4; nt++) {
            acc[nt] = __builtin_amdgcn_mfma_f32_16x16x32_bf16(ah, bq[nt], acc[nt], 0, 0, 0);
            acc[nt] = __builtin_amdgcn_mfma_f32_16x16x32_bf16(ah, bh[nt], acc[nt], 0, 0, 0);
        }
    }

    float aSv[4], aDv[4];
#pragma unroll
    for (int nt = 0; nt < 4; nt++) {
        aSv[nt] = a_src[nt * 16 + l15];
        aDv[nt] = a_dst[nt * 16 + l15];
    }
#pragma unroll
    for (int j = 0; j < 4; j++) {
        int r = row0 + wid * 16 + chunk * 4 + j;
        if (r < M) {
#pragma unroll
            for (int nt = 0; nt < 4; nt++)
                Chi[(size_t)r * N + nt * 16 + l15] = f2bf(acc[nt][j]);
        }
        float s = 0.f, d = 0.f;
#pragma unroll
        for (int nt = 0; nt < 4; nt++) {
            s += acc[nt][j] * aSv[nt];
            d += acc[nt][j] * aDv[nt];
        }
#pragma unroll
        for (int off = 1; off < 16; off <<= 1) {
            s += __shfl_xor(s, off);
            d += __shfl_xor(d, off);
        }
        if (l15 == 0 && r < M) {
            alS[r] = s;
            alD[r] = d;
        }
    }
}

// ---------------- SINGLE-PASS fused softmax + gather, H=4 ----------------
// Block = 128 (2 nodes). 16-edge outer blocks: each lane computes exactly ONE
// exp covering (edge = lane&15, head = lane>>4); two 8-edge inner halves
// consume shfl broadcasts. Masked tail (clamped loads, zeroed weights).
__global__ __launch_bounds__(128) void gather4f(
        const float* __restrict__ alS, const float* __restrict__ alD,
        const ushortt* __restrict__ h,
        const int* __restrict__ ptr, const int* __restrict__ ssrc,
        const float* __restrict__ bias, ushortt* __restrict__ outA, int n) {
    int w = threadIdx.x >> 6, lane = threadIdx.x & 63;
    int node = blockIdx.x * 2 + w;
    if (node >= n) return;
    int p0 = ptr[node], p1 = ptr[node + 1];
    int head = lane >> 4;
    int gbase = lane & 48;   // head * 16
    float adh = alD[node * 4 + head];
    const ushort4* h4 = (const ushort4*)h;
    float4 acc0 = make_float4(0.f, 0.f, 0.f, 0.f);
    float4 acc1 = make_float4(0.f, 0.f, 0.f, 0.f);
    float sum = 0.f;
    int eL = p1 - 1;

#pragma unroll 1
    for (int i = p0; i < p1; i += 16) {
        // one exp per lane for this 16-edge block (edge lane&15, own head)
        int jj = i + (lane & 15);
        int oj = ssrc[min(jj, eL)];
        float wme = __expf(lrelu(alS[(oj >> 4) + head] + adh));
        if (jj > eL) wme = 0.f;

#pragma unroll
        for (int half = 0; half < 2; half++) {
            int base = i + half * 8;
            if (base > eL) break;
            int j0 = min(base + 0, eL), j1 = min(base + 1, eL);
            int j2 = min(base + 2, eL), j3 = min(base + 3, eL);
            int j4 = min(base + 4, eL), j5 = min(base + 5, eL);
            int j6 = min(base + 6, eL), j7 = min(base + 7, eL);
            int o0 = ssrc[j0], o1 = ssrc[j1], o2 = ssrc[j2], o3 = ssrc[j3];
            int o4 = ssrc[j4], o5 = ssrc[j5], o6 = ssrc[j6], o7 = ssrc[j7];
            int hb = gbase + half * 8;
            float w0 = __shfl(wme, hb + 0);
            float w1 = __shfl(wme, hb + 1);
            float w2 = __shfl(wme, hb + 2);
            float w3 = __shfl(wme, hb + 3);
            float w4 = __shfl(wme, hb + 4);
            float w5 = __shfl(wme, hb + 5);
            float w6 = __shfl(wme, hb + 6);
            float w7 = __shfl(wme, hb + 7);
            ushort4 u0 = h4[o0 + lane];
            ushort4 u1 = h4[o1 + lane];
            ushort4 u2 = h4[o2 + lane];
            ushort4 u3 = h4[o3 + lane];
            ushort4 u4 = h4[o4 + lane];
            ushort4 u5 = h4[o5 + lane];
            ushort4 u6 = h4[o6 + lane];
            ushort4 u7 = h4[o7 + lane];
            sum += w0 + w1 + w2 + w3 + w4 + w5 + w6 + w7;
            acc0.x += bf2f(u0.x)*w0; acc0.y += bf2f(u0.y)*w0; acc0.z += bf2f(u0.z)*w0; acc0.w += bf2f(u0.w)*w0;
            acc1.x += bf2f(u1.x)*w1; acc1.y += bf2f(u1.y)*w1; acc1.z += bf2f(u1.z)*w1; acc1.w += bf2f(u1.w)*w1;
            acc0.x += bf2f(u2.x)*w2; acc0.y += bf2f(u2.y)*w2; acc0.z += bf2f(u2.z)*w2; acc0.w += bf2f(u2.w)*w2;
            acc1.x += bf2f(u3.x)*w3; acc1.y += bf2f(u3.y)*w3; acc1.z += bf2f(u3.z)*w3; acc1.w += bf2f(u3.w)*w3;
            acc0.x += bf2f(u4.x)*w4; acc0.y += bf2f(u4.y)*w4; acc0.z += bf2f(u4.z)*w4; acc0.w += bf2f(u4.w)*w4;
            acc1.x += bf2f(u5.x)*w5; acc1.y += bf2f(u5.y)*w5; acc1.z += bf2f(u5.z)*w5; acc1.w += bf2f(u5.w)*w5;
            acc0.x += bf2f(u6.x)*w6; acc0.y += bf2f(u6.y)*w6; acc0.z += bf2f(u6.z)*w6; acc0.w += bf2f(u6.w)*w6;
            acc1.x += bf2f(u7.x)*w7; acc1.y += bf2f(u7.y)*w7; acc1.z += bf2f(u7.z)*w7; acc1.w += bf2f(u7.w)*w7;
        }
    }
    float invh = 1.f / (sum + 1e-16f);
    acc0.x = (acc0.x + acc1.x) * invh;
    acc0.y = (acc0.y + acc1.y) * invh;
    acc0.z = (acc0.z + acc1.z) * invh;
    acc0.w = (acc0.w + acc1.w) * invh;

    float4 b = ((const float4*)bias)[lane];
    ushort4 oh;
    oh.x = f2bf(elu1(acc0.x + b.x));
    oh.y = f2bf(elu1(acc0.y + b.y));
    oh.z = f2bf(elu1(acc0.z + b.z));
    oh.w = f2bf(elu1(acc0.w + b.w));
    ((ushort4*)outA)[(size_t)node * 64 + lane] = oh;
}

// ---------------- SINGLE-PASS fused softmax + gather, H=1 (layer 3) --------
// 8 edge slots x 8 lanes; each lane covers 8 channels (ushort8 = 16 B).
__global__ __launch_bounds__(256) void gather1f(
        const float* __restrict__ alS, const float* __restrict__ alD,
        const ushortt* __restrict__ h,
        const int* __restrict__ ptr, const int* __restrict__ ssrc,
        const float* __restrict__ bias, float* __restrict__ out, int n) {
    int w = threadIdx.x >> 6, lane = threadIdx.x & 63;
    int node = blockIdx.x * 4 + w;
    if (node >= n) return;
    int p0 = ptr[node], p1 = ptr[node + 1];
    float ad = alD[node];
    int eslot = lane >> 3, cl = lane & 7;     // 8 slots, 8 ch-groups of 8
    const short8v* h8 = (const short8v*)h;    // 8 bf16 per element
    float acc[8] = {0.f, 0.f, 0.f, 0.f, 0.f, 0.f, 0.f, 0.f};
    float sum = 0.f;

#pragma unroll 1
    for (int i = p0 + eslot; i < p1; i += 8) {
        int o = ssrc[i];
        float wv = __expf(lrelu(alS[o >> 6] + ad));   // alS[src]
        short8v u = h8[(o >> 3) + cl];                // row base (src*64)/8 + cl
        sum += wv;
#pragma unroll
        for (int k = 0; k < 8; k++)
            acc[k] += bf2f((ushortt)u[k]) * wv;
    }
    // reduce acc and sum across the 8 edge slots
#pragma unroll
    for (int off = 8; off < 64; off <<= 1) {
#pragma unroll
        for (int k = 0; k < 8; k++) acc[k] += __shfl_xor(acc[k], off);
        sum += __shfl_xor(sum, off);
    }
    if (eslot == 0) {
        float inv = 1.f / (sum + 1e-16f);
        const float* bp = bias + cl * 8;
        float o0[8];
#pragma unroll
        for (int k = 0; k < 8; k++) o0[k] = elu1(acc[k] * inv + bp[k]);
        float4* op = (float4*)(out + (size_t)node * 64 + cl * 8);
        op[0] = make_float4(o0[0], o0[1], o0[2], o0[3]);
        op[1] = make_float4(o0[4], o0[5], o0[6], o0[7]);
    }
}

// ---------------- launch ----------------
extern "C" void kernel_launch(void* const* d_in, const int* in_sizes, int n_in,
                              void* d_out, int out_size, void* d_ws, size_t ws_size,
                              hipStream_t stream) {
    const float* x      = (const float*)d_in[0];
    const int*   eidx   = (const int*)d_in[1];
    const float* W1     = (const float*)d_in[2];
    const float* a_src1 = (const float*)d_in[3];
    const float* a_dst1 = (const float*)d_in[4];
    const float* b1     = (const float*)d_in[5];
    const float* W2     = (const float*)d_in[6];
    const float* a_src2 = (const float*)d_in[7];
    const float* a_dst2 = (const float*)d_in[8];
    const float* b2     = (const float*)d_in[9];
    const float* W3     = (const float*)d_in[10];
    const float* a_src3 = (const float*)d_in[11];
    const float* a_dst3 = (const float*)d_in[12];
    const float* b3     = (const float*)d_in[13];

    const int n = in_sizes[0] / IN_DIM;       // 50000
    const int E = in_sizes[1] / 2;            // 800000
    const int* srcp = eidx;
    const int* dstp = eidx + E;

    size_t off = 0;
    auto alloc = [&](size_t bytes) {
        void* p = (char*)d_ws + off;
        off += (bytes + 255) & ~(size_t)255;
        return p;
    };
    int*     ptr    = (int*)alloc((size_t)(n + 1) * 4);
    int*     work   = (int*)alloc((size_t)n * 4);
    int*     bsums  = (int*)alloc(256 * 4);
    int*     ssrc   = (int*)alloc((size_t)E * 4);
    ushortt* Ai0    = (ushortt*)alloc((size_t)n * HC * 2);   // bf16 row-major A
    ushortt* Ai1    = (ushortt*)alloc((size_t)n * HC * 2);
    ushortt* hbf    = (ushortt*)alloc((size_t)n * HC * 2);   // GEMM out (bf16)
    float*   alS    = (float*)alloc((size_t)n * HEADS * 4);
    float*   alD    = (float*)alloc((size_t)n * HEADS * 4);
    ushortt* Wt1    = (ushortt*)alloc((size_t)256 * HC * 2 * 2);
    ushortt* Wt2    = (ushortt*)alloc((size_t)256 * HC * 2 * 2);
    ushortt* Wt3    = (ushortt*)alloc((size_t)256 * OUTC * 2 * 2);
    (void)ws_size;

    // ---- CSR build + W prep (fused first kernel) ----
    hipMemsetAsync(work, 0, (size_t)n * 4, stream);
    int cblocks = 576 + (E + 255) / 256;
    count_prep<<<cblocks, 256, 0, stream>>>(W1, W2, W3, Wt1, Wt2, Wt3,
                                            dstp, work, E);

    int gblocks = (n + 63) / 64;   // 782
    int nb = (n + 1023) / 1024;    // 49 scan blocks
    int node2 = (n + 1) / 2;
    int node4 = (n + 3) / 4;

    // ---- layer 1 GEMM + fused CSR block-scan (independent work) ----
    gemm_mfma<true><<<gblocks + nb, 256, 0, stream>>>(
        nullptr, x, Wt1, hbf, n, a_src1, a_dst1, alS, alD,
        work, ptr, bsums, n, gblocks);
    // ---- finish CSR ----
    scan_add<<<(n + 255) / 256, 256, 0, stream>>>(ptr, bsums, work, n);
    scatter_edges<<<(E + 255) / 256, 256, 0, stream>>>(srcp, dstp, work, ssrc, E);

    // ---- layer 1 gather ----
    gather4f<<<node2, 128, 0, stream>>>(alS, alD, hbf, ptr, ssrc, b1, Ai1, n);

    // ---- layer 2 ----
    gemm_mfma<false><<<gblocks, 256, 0, stream>>>(
        Ai1, nullptr, Wt2, hbf, n, a_src2, a_dst2, alS, alD,
        nullptr, nullptr, nullptr, 0, gblocks);
    gather4f<<<node2, 128, 0, stream>>>(alS, alD, hbf, ptr, ssrc, b2, Ai0, n);

    // ---- layer 3 ----
    gemm_n64<<<gblocks, 256, 0, stream>>>(
        Ai0, Wt3, hbf, n, a_src3, a_dst3, alS, alD);
    gather1f<<<node4, 256, 0, stream>>>(alS, alD, hbf, ptr, ssrc, b3,
                                        (float*)d_out, n);
}

// Round 21
// 348.275 us; speedup vs baseline: 1.0198x; 1.0198x over previous
//
#include <hip/hip_runtime.h>
#include <hip/hip_bf16.h>
#include <math.h>

// ---------------- constants ----------------
#define IN_DIM 256
#define HID 64
#define HEADS 4
#define HC (HEADS * HID)   // 256
#define OUTC 64
#define NEG_SLOPE 0.2f

typedef unsigned int uint;
typedef unsigned short ushortt;
typedef __attribute__((ext_vector_type(8))) short short8v;
typedef __attribute__((ext_vector_type(4))) float floatx4;

union U8 { uint u[4]; short8v v; };

__device__ __forceinline__ float lrelu(float x) {
    return x >= 0.f ? x : NEG_SLOPE * x;
}
__device__ __forceinline__ float elu1(float x) {
    return x > 0.f ? x : expm1f(x);
}
__device__ __forceinline__ ushortt f2bf(float f) {   // RNE
    uint x = __float_as_uint(f);
    uint r = (x + 0x7fffu + ((x >> 16) & 1u)) >> 16;
    return (ushortt)r;
}
__device__ __forceinline__ float bf2f(ushortt u) {
    return __uint_as_float(((uint)u) << 16);
}

// pack 2 floats -> (hi bf16 pair, lo bf16 pair), RNE (matches f2bf bit-exactly)
#define CVTPAIR(fx, fy, ho, qo)                                                 \
    asm("v_cvt_pk_bf16_f32 %0, %1, %2" : "=v"(ho) : "v"(fx), "v"(fy));          \
    {                                                                           \
        float _r0 = (fx) - __uint_as_float((ho) << 16);                         \
        float _r1 = (fy) - __uint_as_float((ho) & 0xffff0000u);                 \
        asm("v_cvt_pk_bf16_f32 %0, %1, %2" : "=v"(qo) : "v"(_r0), "v"(_r1));    \
    }

// ---------------- W split body (interleaved planes) ----------------
// W layout: Wt[kb(32)][col(N)][hi8|lo8]
__device__ __forceinline__ void wsplit_body(const float* __restrict__ W,
                                            ushortt* __restrict__ Wt, int N,
                                            int b, int tid) {
    int idx = b * 256 + tid;            // < 256*N
    int j = idx & 7;
    int col = (idx >> 3) % N;
    int kb = (idx >> 3) / N;            // 0..31
    float wv = W[(size_t)(kb * 8 + j) * N + col];
    ushortt hi = f2bf(wv);
    ushortt lo = f2bf(wv - bf2f(hi));
    size_t o = ((size_t)kb * N + col) * 16 + j;
    Wt[o] = hi;
    Wt[o + 8] = lo;
}

// ---------------- fused: W splits + edge counting ----------------
__global__ __launch_bounds__(256) void count_prep(
        const float* __restrict__ W1, const float* __restrict__ W2,
        const float* __restrict__ W3,
        ushortt* __restrict__ Wt1, ushortt* __restrict__ Wt2,
        ushortt* __restrict__ Wt3,
        const int* __restrict__ dst, int* __restrict__ counts, int E) {
    int b = blockIdx.x, tid = threadIdx.x;
    if (b < 256) { wsplit_body(W1, Wt1, 256, b, tid); return; }
    if (b < 512) { wsplit_body(W2, Wt2, 256, b - 256, tid); return; }
    if (b < 576) { wsplit_body(W3, Wt3, 64, b - 512, tid); return; }
    int e = (b - 576) * 256 + tid;
    if (e < E) atomicAdd(&counts[dst[e]], 1);
}

// merged bsums-prefix + add; also writes work[] = ptr[] (start offsets)
__global__ void scan_add(int* __restrict__ ptr, const int* __restrict__ bsums,
                         int* __restrict__ work, int n) {
    __shared__ int pre;
    int seg = blockIdx.x >> 2;
    if (threadIdx.x == 0) {
        int s = 0;
        for (int b = 0; b < seg; b++) s += bsums[b];
        pre = s;
    }
    __syncthreads();
    int i = blockIdx.x * 256 + threadIdx.x;
    if (i == 0) { ptr[0] = 0; work[0] = 0; }
    if (i < n) {
        int v = ptr[i + 1] + pre;
        ptr[i + 1] = v;
        if (i + 1 < n) work[i + 1] = v;
    }
}

// stores src*64 (pre-scaled row index)
__global__ void scatter_edges(const int* __restrict__ src, const int* __restrict__ dst,
                              int* __restrict__ work, int* __restrict__ ssrc, int E) {
    int e = blockIdx.x * blockDim.x + threadIdx.x;
    if (e < E) {
        int p = atomicAdd(&work[dst[e]], 1);
        ssrc[p] = src[e] * 64;
    }
}

// ---------------- MFMA GEMM layers 1/2: N=256, 2x2 wave tiling ------------
// F32A (layer 1): fp32 A, 3-term split-bf16, hosts the CSR block-scan in
// extra blocks. !F32A (layer 2): bf16 row-major A (single plane), 2-term.
template<bool F32A>
__global__ __launch_bounds__(256, 3) void gemm_mfma(
        const ushortt* __restrict__ Ai, const float* __restrict__ Af,
        const ushortt* __restrict__ Wt,
        ushortt* __restrict__ Chi, int M,
        const float* __restrict__ a_src, const float* __restrict__ a_dst,
        float* __restrict__ alS, float* __restrict__ alD,
        const int* __restrict__ counts, int* __restrict__ ptrOut,
        int* __restrict__ bsums, int nScan, int gemmBlocks) {
    constexpr int N = 256;
    if constexpr (F32A) {
        if ((int)blockIdx.x >= gemmBlocks) {
            // ---- block scan of counts (1024 per block) ----
            __shared__ int sm[256];
            int sb = blockIdx.x - gemmBlocks;
            int t = threadIdx.x;
            int i = sb * 1024 + t * 4;
            int v0 = 0, v1 = 0, v2 = 0, v3 = 0;
            if (i + 0 < nScan) v0 = counts[i + 0];
            if (i + 1 < nScan) v1 = counts[i + 1];
            if (i + 2 < nScan) v2 = counts[i + 2];
            if (i + 3 < nScan) v3 = counts[i + 3];
            int s1 = v0 + v1, s2 = s1 + v2, s3 = s2 + v3;
            sm[t] = s3;
            __syncthreads();
            for (int off = 1; off < 256; off <<= 1) {
                int add = (t >= off) ? sm[t - off] : 0;
                __syncthreads();
                sm[t] += add;
                __syncthreads();
            }
            int pre = (t > 0) ? sm[t - 1] : 0;
            if (i + 0 < nScan) ptrOut[i + 1] = pre + v0;
            if (i + 1 < nScan) ptrOut[i + 2] = pre + s1;
            if (i + 2 < nScan) ptrOut[i + 3] = pre + s2;
            if (i + 3 < nScan) ptrOut[i + 4] = pre + s3;
            if (t == 255) bsums[sb] = sm[255];
            return;
        }
    }

    int t = threadIdx.x;
    int wid = t >> 6, l = t & 63, l15 = l & 15, chunk = l >> 4;
    int wr = wid >> 1, wc = wid & 1;
    int row0 = blockIdx.x * 64;
    int colw = wc * 128;

    floatx4 acc[2][8];
    floatx4 zero = {0.f, 0.f, 0.f, 0.f};
#pragma unroll
    for (int mt = 0; mt < 2; mt++)
#pragma unroll
        for (int nt = 0; nt < 8; nt++) acc[mt][nt] = zero;

    size_t arow[2];
#pragma unroll
    for (int mt = 0; mt < 2; mt++) {
        int r = row0 + wr * 32 + mt * 16 + l15;
        int rc = r < M ? r : M - 1;
        arow[mt] = (size_t)rc * 256;
    }

    for (int ks = 0; ks < 8; ks++) {
        int kb = ks * 4 + chunk;
        short8v ah[2], aq[2];
        if constexpr (F32A) {
#pragma unroll
            for (int mt = 0; mt < 2; mt++) {
                const float* ap = Af + arow[mt] + kb * 8;
                float4 a0 = ((const float4*)ap)[0];
                float4 a1 = ((const float4*)ap)[1];
                U8 h, q;
                CVTPAIR(a0.x, a0.y, h.u[0], q.u[0]);
                CVTPAIR(a0.z, a0.w, h.u[1], q.u[1]);
                CVTPAIR(a1.x, a1.y, h.u[2], q.u[2]);
                CVTPAIR(a1.z, a1.w, h.u[3], q.u[3]);
                ah[mt] = h.v; aq[mt] = q.v;
            }
        } else {
#pragma unroll
            for (int mt = 0; mt < 2; mt++) {
                ah[mt] = *(const short8v*)(Ai + arow[mt] + kb * 8);
            }
        }
        const ushortt* bbase = Wt + ((size_t)kb * N + colw + l15) * 16;
#pragma unroll
        for (int half = 0; half < 2; half++) {
            short8v bh[4], bq[4];
#pragma unroll
            for (int nt = 0; nt < 4; nt++) {
                const ushortt* bp = bbase + (size_t)(half * 4 + nt) * 256;
                bh[nt] = *(const short8v*)bp;
                bq[nt] = *(const short8v*)(bp + 8);
            }
#pragma unroll
            for (int mt = 0; mt < 2; mt++)
#pragma unroll
                for (int nt = 0; nt < 4; nt++) {
                    int c = half * 4 + nt;
                    if constexpr (F32A)
                        acc[mt][c] = __builtin_amdgcn_mfma_f32_16x16x32_bf16(aq[mt], bh[nt], acc[mt][c], 0, 0, 0);
                    acc[mt][c] = __builtin_amdgcn_mfma_f32_16x16x32_bf16(ah[mt], bq[nt], acc[mt][c], 0, 0, 0);
                    acc[mt][c] = __builtin_amdgcn_mfma_f32_16x16x32_bf16(ah[mt], bh[nt], acc[mt][c], 0, 0, 0);
                }
        }
    }

    // C store
#pragma unroll
    for (int mt = 0; mt < 2; mt++)
#pragma unroll
        for (int j = 0; j < 4; j++) {
            int r = row0 + wr * 32 + mt * 16 + chunk * 4 + j;
            if (r < M) {
#pragma unroll
                for (int nt = 0; nt < 8; nt++)
                    Chi[(size_t)r * N + colw + nt * 16 + l15] = f2bf(acc[mt][nt][j]);
            }
        }

    // fused attention logits: this wave covers heads wc*2 and wc*2+1
    {
        float aSv[8], aDv[8];
#pragma unroll
        for (int nt = 0; nt < 8; nt++) {
            aSv[nt] = a_src[colw + nt * 16 + l15];
            aDv[nt] = a_dst[colw + nt * 16 + l15];
        }
#pragma unroll
        for (int mt = 0; mt < 2; mt++)
#pragma unroll
            for (int j = 0; j < 4; j++) {
                float s0 = 0.f, d0 = 0.f, s1 = 0.f, d1 = 0.f;
#pragma unroll
                for (int nt = 0; nt < 4; nt++) {
                    s0 += acc[mt][nt][j] * aSv[nt];
                    d0 += acc[mt][nt][j] * aDv[nt];
                    s1 += acc[mt][nt + 4][j] * aSv[nt + 4];
                    d1 += acc[mt][nt + 4][j] * aDv[nt + 4];
                }
#pragma unroll
                for (int off = 1; off < 16; off <<= 1) {
                    s0 += __shfl_xor(s0, off);
                    d0 += __shfl_xor(d0, off);
                    s1 += __shfl_xor(s1, off);
                    d1 += __shfl_xor(d1, off);
                }
                int r = row0 + wr * 32 + mt * 16 + chunk * 4 + j;
                if (l15 == 0 && r < M) {
                    alS[(size_t)r * 4 + wc * 2 + 0] = s0;
                    alS[(size_t)r * 4 + wc * 2 + 1] = s1;
                    alD[(size_t)r * 4 + wc * 2 + 0] = d0;
                    alD[(size_t)r * 4 + wc * 2 + 1] = d1;
                }
            }
    }
}

// ---------------- MFMA GEMM layer 3: N=64, bf16 A (row-major), 2-term ----
__global__ __launch_bounds__(256) void gemm_n64(
        const ushortt* __restrict__ Ai, const ushortt* __restrict__ Wt,
        ushortt* __restrict__ Chi, int M,
        const float* __restrict__ a_src, const float* __restrict__ a_dst,
        float* __restrict__ alS, float* __restrict__ alD) {
    constexpr int N = 64;
    int t = threadIdx.x;
    int wid = t >> 6, l = t & 63, l15 = l & 15, chunk = l >> 4;
    int row0 = blockIdx.x * 64;
    int rw = row0 + wid * 16 + l15;
    size_t arow = (size_t)(rw < M ? rw : M - 1) * 256;

    floatx4 acc[4];
    floatx4 zero = {0.f, 0.f, 0.f, 0.f};
#pragma unroll
    for (int nt = 0; nt < 4; nt++) acc[nt] = zero;

    for (int ks = 0; ks < 8; ks++) {
        int kb = ks * 4 + chunk;
        short8v bh[4], bq[4];
#pragma unroll
        for (int nt = 0; nt < 4; nt++) {
            const ushortt* bp = Wt + ((size_t)kb * N + nt * 16 + l15) * 16;
            bh[nt] = *(const short8v*)bp;
            bq[nt] = *(const short8v*)(bp + 8);
        }
        short8v ah = *(const short8v*)(Ai + arow + kb * 8);
#pragma unroll
        for (int nt = 0; nt < 4; nt++) {
            acc[nt] = __builtin_amdgcn_mfma_f32_16x16x32_bf16(ah, bq[nt], acc[nt], 0, 0, 0);
            acc[nt] = __builtin_amdgcn_mfma_f32_16x16x32_bf16(ah, bh[nt], acc[nt], 0, 0, 0);
        }
    }

    float aSv[4], aDv[4];
#pragma unroll
    for (int nt = 0; nt < 4; nt++) {
        aSv[nt] = a_src[nt * 16 + l15];
        aDv[nt] = a_dst[nt * 16 + l15];
    }
#pragma unroll
    for (int j = 0; j < 4; j++) {
        int r = row0 + wid * 16 + chunk * 4 + j;
        if (r < M) {
#pragma unroll
            for (int nt = 0; nt < 4; nt++)
                Chi[(size_t)r * N + nt * 16 + l15] = f2bf(acc[nt][j]);
        }
        float s = 0.f, d = 0.f;
#pragma unroll
        for (int nt = 0; nt < 4; nt++) {
            s += acc[nt][j] * aSv[nt];
            d += acc[nt][j] * aDv[nt];
        }
#pragma unroll
        for (int off = 1; off < 16; off <<= 1) {
            s += __shfl_xor(s, off);
            d += __shfl_xor(d, off);
        }
        if (l15 == 0 && r < M) {
            alS[r] = s;
            alD[r] = d;
        }
    }
}

// ---------------- SINGLE-PASS fused softmax + gather, H=4 ----------------
// Block = 128 (2 nodes). Exp dedup via shfl broadcast (8-edge blocks).
// Masked tail: clamped indices, zeroed weights for padded slots.
__global__ __launch_bounds__(128) void gather4f(
        const float* __restrict__ alS, const float* __restrict__ alD,
        const ushortt* __restrict__ h,
        const int* __restrict__ ptr, const int* __restrict__ ssrc,
        const float* __restrict__ bias, ushortt* __restrict__ outA, int n) {
    int w = threadIdx.x >> 6, lane = threadIdx.x & 63;
    int node = blockIdx.x * 2 + w;
    if (node >= n) return;
    int p0 = ptr[node], p1 = ptr[node + 1];
    int head = lane >> 4;
    int gbase = lane & 48;   // head * 16
    float adh = alD[node * 4 + head];
    const ushort4* h4 = (const ushort4*)h;
    float4 acc0 = make_float4(0.f, 0.f, 0.f, 0.f);
    float4 acc1 = make_float4(0.f, 0.f, 0.f, 0.f);
    float sum = 0.f;
    int e7 = p1 - 1;

#pragma unroll 1
    for (int i = p0; i < p1; i += 8) {
        int j0 = i + 0, j1 = min(i + 1, e7), j2 = min(i + 2, e7), j3 = min(i + 3, e7);
        int j4 = min(i + 4, e7), j5 = min(i + 5, e7), j6 = min(i + 6, e7), j7 = min(i + 7, e7);
        int o0 = ssrc[j0], o1 = ssrc[j1], o2 = ssrc[j2], o3 = ssrc[j3];
        int o4 = ssrc[j4], o5 = ssrc[j5], o6 = ssrc[j6], o7 = ssrc[j7];
        // one exp per lane: edge = lane&7 of this block, zero if padded
        int jj = i + (lane & 7);
        int oj = ssrc[min(jj, e7)];
        float wme = __expf(lrelu(alS[(oj >> 4) + head] + adh));
        if (jj > e7) wme = 0.f;
        float w0 = __shfl(wme, gbase + 0);
        float w1 = __shfl(wme, gbase + 1);
        float w2 = __shfl(wme, gbase + 2);
        float w3 = __shfl(wme, gbase + 3);
        float w4 = __shfl(wme, gbase + 4);
        float w5 = __shfl(wme, gbase + 5);
        float w6 = __shfl(wme, gbase + 6);
        float w7 = __shfl(wme, gbase + 7);
        ushort4 u0 = h4[o0 + lane];
        ushort4 u1 = h4[o1 + lane];
        ushort4 u2 = h4[o2 + lane];
        ushort4 u3 = h4[o3 + lane];
        ushort4 u4 = h4[o4 + lane];
        ushort4 u5 = h4[o5 + lane];
        ushort4 u6 = h4[o6 + lane];
        ushort4 u7 = h4[o7 + lane];
        sum += w0 + w1 + w2 + w3 + w4 + w5 + w6 + w7;
        acc0.x += bf2f(u0.x)*w0; acc0.y += bf2f(u0.y)*w0; acc0.z += bf2f(u0.z)*w0; acc0.w += bf2f(u0.w)*w0;
        acc1.x += bf2f(u1.x)*w1; acc1.y += bf2f(u1.y)*w1; acc1.z += bf2f(u1.z)*w1; acc1.w += bf2f(u1.w)*w1;
        acc0.x += bf2f(u2.x)*w2; acc0.y += bf2f(u2.y)*w2; acc0.z += bf2f(u2.z)*w2; acc0.w += bf2f(u2.w)*w2;
        acc1.x += bf2f(u3.x)*w3; acc1.y += bf2f(u3.y)*w3; acc1.z += bf2f(u3.z)*w3; acc1.w += bf2f(u3.w)*w3;
        acc0.x += bf2f(u4.x)*w4; acc0.y += bf2f(u4.y)*w4; acc0.z += bf2f(u4.z)*w4; acc0.w += bf2f(u4.w)*w4;
        acc1.x += bf2f(u5.x)*w5; acc1.y += bf2f(u5.y)*w5; acc1.z += bf2f(u5.z)*w5; acc1.w += bf2f(u5.w)*w5;
        acc0.x += bf2f(u6.x)*w6; acc0.y += bf2f(u6.y)*w6; acc0.z += bf2f(u6.z)*w6; acc0.w += bf2f(u6.w)*w6;
        acc1.x += bf2f(u7.x)*w7; acc1.y += bf2f(u7.y)*w7; acc1.z += bf2f(u7.z)*w7; acc1.w += bf2f(u7.w)*w7;
    }
    float invh = 1.f / (sum + 1e-16f);
    acc0.x = (acc0.x + acc1.x) * invh;
    acc0.y = (acc0.y + acc1.y) * invh;
    acc0.z = (acc0.z + acc1.z) * invh;
    acc0.w = (acc0.w + acc1.w) * invh;

    float4 b = ((const float4*)bias)[lane];
    ushort4 oh;
    oh.x = f2bf(elu1(acc0.x + b.x));
    oh.y = f2bf(elu1(acc0.y + b.y));
    oh.z = f2bf(elu1(acc0.z + b.z));
    oh.w = f2bf(elu1(acc0.w + b.w));
    ((ushort4*)outA)[(size_t)node * 64 + lane] = oh;
}

// ---------------- SINGLE-PASS fused softmax + gather, H=1 (layer 3) --------
// 8 edge slots x 8 lanes; each lane covers 8 channels (ushort8 = 16 B).
__global__ __launch_bounds__(256) void gather1f(
        const float* __restrict__ alS, const float* __restrict__ alD,
        const ushortt* __restrict__ h,
        const int* __restrict__ ptr, const int* __restrict__ ssrc,
        const float* __restrict__ bias, float* __restrict__ out, int n) {
    int w = threadIdx.x >> 6, lane = threadIdx.x & 63;
    int node = blockIdx.x * 4 + w;
    if (node >= n) return;
    int p0 = ptr[node], p1 = ptr[node + 1];
    float ad = alD[node];
    int eslot = lane >> 3, cl = lane & 7;     // 8 slots, 8 ch-groups of 8
    const short8v* h8 = (const short8v*)h;    // 8 bf16 per element
    float acc[8] = {0.f, 0.f, 0.f, 0.f, 0.f, 0.f, 0.f, 0.f};
    float sum = 0.f;

#pragma unroll 1
    for (int i = p0 + eslot; i < p1; i += 8) {
        int o = ssrc[i];
        float wv = __expf(lrelu(alS[o >> 6] + ad));   // alS[src]
        short8v u = h8[(o >> 3) + cl];                // row base (src*64)/8 + cl
        sum += wv;
#pragma unroll
        for (int k = 0; k < 8; k++)
            acc[k] += bf2f((ushortt)u[k]) * wv;
    }
    // reduce acc and sum across the 8 edge slots
#pragma unroll
    for (int off = 8; off < 64; off <<= 1) {
#pragma unroll
        for (int k = 0; k < 8; k++) acc[k] += __shfl_xor(acc[k], off);
        sum += __shfl_xor(sum, off);
    }
    if (eslot == 0) {
        float inv = 1.f / (sum + 1e-16f);
        const float* bp = bias + cl * 8;
        float o0[8];
#pragma unroll
        for (int k = 0; k < 8; k++) o0[k] = elu1(acc[k] * inv + bp[k]);
        float4* op = (float4*)(out + (size_t)node * 64 + cl * 8);
        op[0] = make_float4(o0[0], o0[1], o0[2], o0[3]);
        op[1] = make_float4(o0[4], o0[5], o0[6], o0[7]);
    }
}

// ---------------- launch ----------------
extern "C" void kernel_launch(void* const* d_in, const int* in_sizes, int n_in,
                              void* d_out, int out_size, void* d_ws, size_t ws_size,
                              hipStream_t stream) {
    const float* x      = (const float*)d_in[0];
    const int*   eidx   = (const int*)d_in[1];
    const float* W1     = (const float*)d_in[2];
    const float* a_src1 = (const float*)d_in[3];
    const float* a_dst1 = (const float*)d_in[4];
    const float* b1     = (const float*)d_in[5];
    const float* W2     = (const float*)d_in[6];
    const float* a_src2 = (const float*)d_in[7];
    const float* a_dst2 = (const float*)d_in[8];
    const float* b2     = (const float*)d_in[9];
    const float* W3     = (const float*)d_in[10];
    const float* a_src3 = (const float*)d_in[11];
    const float* a_dst3 = (const float*)d_in[12];
    const float* b3     = (const float*)d_in[13];

    const int n = in_sizes[0] / IN_DIM;       // 50000
    const int E = in_sizes[1] / 2;            // 800000
    const int* srcp = eidx;
    const int* dstp = eidx + E;

    size_t off = 0;
    auto alloc = [&](size_t bytes) {
        void* p = (char*)d_ws + off;
        off += (bytes + 255) & ~(size_t)255;
        return p;
    };
    int*     ptr    = (int*)alloc((size_t)(n + 1) * 4);
    int*     work   = (int*)alloc((size_t)n * 4);
    int*     bsums  = (int*)alloc(256 * 4);
    int*     ssrc   = (int*)alloc((size_t)E * 4);
    ushortt* Ai0    = (ushortt*)alloc((size_t)n * HC * 2);   // bf16 row-major A
    ushortt* Ai1    = (ushortt*)alloc((size_t)n * HC * 2);
    ushortt* hbf    = (ushortt*)alloc((size_t)n * HC * 2);   // GEMM out (bf16)
    float*   alS    = (float*)alloc((size_t)n * HEADS * 4);
    float*   alD    = (float*)alloc((size_t)n * HEADS * 4);
    ushortt* Wt1    = (ushortt*)alloc((size_t)256 * HC * 2 * 2);
    ushortt* Wt2    = (ushortt*)alloc((size_t)256 * HC * 2 * 2);
    ushortt* Wt3    = (ushortt*)alloc((size_t)256 * OUTC * 2 * 2);
    (void)ws_size;

    // ---- CSR build + W prep (fused first kernel) ----
    hipMemsetAsync(work, 0, (size_t)n * 4, stream);
    int cblocks = 576 + (E + 255) / 256;
    count_prep<<<cblocks, 256, 0, stream>>>(W1, W2, W3, Wt1, Wt2, Wt3,
                                            dstp, work, E);

    int gblocks = (n + 63) / 64;   // 782
    int nb = (n + 1023) / 1024;    // 49 scan blocks
    int node2 = (n + 1) / 2;
    int node4 = (n + 3) / 4;

    // ---- layer 1 GEMM + fused CSR block-scan (independent work) ----
    gemm_mfma<true><<<gblocks + nb, 256, 0, stream>>>(
        nullptr, x, Wt1, hbf, n, a_src1, a_dst1, alS, alD,
        work, ptr, bsums, n, gblocks);
    // ---- finish CSR ----
    scan_add<<<(n + 255) / 256, 256, 0, stream>>>(ptr, bsums, work, n);
    scatter_edges<<<(E + 255) / 256, 256, 0, stream>>>(srcp, dstp, work, ssrc, E);

    // ---- layer 1 gather ----
    gather4f<<<node2, 128, 0, stream>>>(alS, alD, hbf, ptr, ssrc, b1, Ai1, n);

    // ---- layer 2 ----
    gemm_mfma<false><<<gblocks, 256, 0, stream>>>(
        Ai1, nullptr, Wt2, hbf, n, a_src2, a_dst2, alS, alD,
        nullptr, nullptr, nullptr, 0, gblocks);
    gather4f<<<node2, 128, 0, stream>>>(alS, alD, hbf, ptr, ssrc, b2, Ai0, n);

    // ---- layer 3 ----
    gemm_n64<<<gblocks, 256, 0, stream>>>(
        Ai0, Wt3, hbf, n, a_src3, a_dst3, alS, alD);
    gather1f<<<node4, 256, 0, stream>>>(alS, alD, hbf, ptr, ssrc, b3,
                                        (float*)d_out, n);
}